// Round 13
// baseline (144.175 us; speedup 1.0000x reference)
//
#include <hip/hip_runtime.h>

#define BATCH 8
#define NUM_GENES 20000
#define FEAT 64

typedef float f32x4 __attribute__((ext_vector_type(4)));

// Pass 1: find segment start offsets from sorted segment_ids.
__global__ __launch_bounds__(256)
void find_starts_kernel(const int* __restrict__ segment_ids,
                        int* __restrict__ starts, int total)
{
    int i = blockIdx.x * 256 + threadIdx.x;
    if (i < total) {
        int s = segment_ids[i];
        if (i == 0 || segment_ids[i - 1] != s) starts[s] = i;
    }
}

// Pass 2: R5 structure (best verified: 32.6 us) + NON-TEMPORAL gathers.
// 256-thread blocks = 4 waves; wave w handles segment group*4+w, batch
// b = bid & 7 (XCD pinning: verified R2, FETCH 157->70 MB). lane =
// sub*16 + fq; sub picks one of 4 gene rows per gather instruction, fq
// the float4 feature quad. Indices staged pre-scaled (idx*FEAT), broadcast
// via __shfl. Depth-8 issue-then-drain sawtooth (verified R5: -25%;
// depth-12, double-buffer, 128-thr shape all neutral; dynamic queue -9x).
// Gather loads use __builtin_nontemporal_load (nt, L1-bypass): L1 is
// ~100%-miss on the 5.12 MB random working set, and the R11 evidence
// (bf16 halved bytes+instrs for only ~10%) points at L1 miss-handling
// as the per-CU service-rate floor. (R12: builtin needs ext_vector_type,
// not HIP's float4 class -- fixed with f32x4.)
__global__ __launch_bounds__(256)
void genesets_pool_kernel(const float* __restrict__ gene,        // [B][G][F]
                          const int*   __restrict__ flat_indices,// [total]
                          const int*   __restrict__ starts,      // [S]
                          const int*   __restrict__ counts,      // [S]
                          float*       __restrict__ out,         // [B][S][F]
                          int num_segments)
{
    const int bid  = blockIdx.x;
    const int b    = bid & 7;                      // batch -> XCD
    const int wave = threadIdx.x >> 6;             // 0..3
    const int s    = (bid >> 3) * 4 + wave;        // segment
    const int lane = threadIdx.x & 63;
    const int sub  = lane >> 4;                    // 0..3
    const int fq   = lane & 15;                    // feature quad

    if (s >= num_segments) return;

    const int start = starts[s];
    const int cnt   = counts[s];

    // Stage all indices, pre-scaled to element offsets (cnt < 128).
    int off_a = (lane      < cnt) ? flat_indices[start + lane]      * FEAT : 0;
    int off_b = (lane + 64 < cnt) ? flat_indices[start + lane + 64] * FEAT : 0;

    const float* gbase = gene + (size_t)b * NUM_GENES * FEAT + fq * 4;

    f32x4 acc = (f32x4)(0.f);
    const int kn = (cnt + 3) >> 2;                 // quads, <= 23

    for (int c = 0; c < kn; c += 8) {
        f32x4 buf[8];
        #pragma unroll
        for (int p = 0; p < 8; ++p) {
            const int j = sub + 4 * (c + p);
            const int off = (j < 64) ? __shfl(off_a, j) : __shfl(off_b, j & 63);
            if (j < cnt) {
                buf[p] = __builtin_nontemporal_load(
                    reinterpret_cast<const f32x4*>(gbase + off));
            } else {
                buf[p] = (f32x4)(0.f);
            }
        }
        #pragma unroll
        for (int p = 0; p < 8; ++p) acc += buf[p];
    }

    // Reduce over the 4 sub-groups (lanes differing in bits 4..5).
    acc.x += __shfl_xor(acc.x, 16); acc.y += __shfl_xor(acc.y, 16);
    acc.z += __shfl_xor(acc.z, 16); acc.w += __shfl_xor(acc.w, 16);
    acc.x += __shfl_xor(acc.x, 32); acc.y += __shfl_xor(acc.y, 32);
    acc.z += __shfl_xor(acc.z, 32); acc.w += __shfl_xor(acc.w, 32);

    if (sub == 0) {
        const float inv = 1.0f / (float)cnt;
        f32x4 r = acc * inv;
        *reinterpret_cast<f32x4*>(out + ((size_t)b * num_segments + s) * FEAT + fq * 4) = r;
    }
}

extern "C" void kernel_launch(void* const* d_in, const int* in_sizes, int n_in,
                              void* d_out, int out_size, void* d_ws, size_t ws_size,
                              hipStream_t stream)
{
    const float* gene         = (const float*)d_in[0];
    const int*   flat_indices = (const int*)d_in[1];
    const int*   segment_ids  = (const int*)d_in[2];
    const int*   counts       = (const int*)d_in[3];
    float*       out          = (float*)d_out;

    const int total        = in_sizes[1];
    const int num_segments = in_sizes[3];

    int* starts = (int*)d_ws;          // num_segments ints of scratch

    find_starts_kernel<<<(total + 255) / 256, 256, 0, stream>>>(segment_ids, starts, total);

    const int seg_groups = (num_segments + 3) / 4;
    const int nblocks    = seg_groups * BATCH;
    genesets_pool_kernel<<<nblocks, 256, 0, stream>>>(gene, flat_indices, starts,
                                                      counts, out, num_segments);
}